// Round 25
// baseline (233.045 us; speedup 1.0000x reference)
//
#include <hip/hip_runtime.h>
#include <hip/hip_fp16.h>
#include <math.h>
#include <stdint.h>
#include <string.h>

typedef unsigned __int128 u128;
typedef _Float16 h2v __attribute__((ext_vector_type(2)));
typedef short    s2v __attribute__((ext_vector_type(2)));

#define NK 10000
#define NBLK 1024          // all-resident grid (4 blocks/CU)

#define PCG_MUL_128 ((((u128)0x2360ed051fc65da4ULL) << 64) | 0x4385df649fccf645ULL)

// d_ws layout: pack[NK] then work counter
#define WS_NEEDED  ((NK + 1) * 4)

struct ThrTab { double t[3][84]; };        // dil thresholds, v = 2..85

// ============================================================================
// numpy default_rng(0) chain (verified r8-r23): SeedSequence mix = x*L - y*R
// (SUBTRACT); PCG64 XSL-RR step-then-output; integers -> buffered Lemire32,
// low half first. Device regenerates draws per-thread via advance() skip-ahead.
// ============================================================================
static void host_seed(u128& state, u128& inc) {
  uint32_t hc = 0x43b0d7e5u;
  auto hashmix = [&hc](uint32_t v) -> uint32_t {
    v ^= hc; hc *= 0x931e8875u; v *= hc; v ^= v >> 16; return v;
  };
  uint32_t pool[4];
  for (int i = 0; i < 4; ++i) pool[i] = hashmix(0u);
  for (int s = 0; s < 4; ++s)
    for (int d = 0; d < 4; ++d)
      if (s != d) {
        uint32_t h = hashmix(pool[s]);
        uint32_t r = pool[d] * 0xca01f9ddu - h * 0x4973f715u;   // subtract
        r ^= r >> 16;
        pool[d] = r;
      }
  uint32_t hb = 0x8b51f9ddu;
  uint32_t w[8];
  for (int i = 0; i < 8; ++i) {
    uint32_t v = pool[i & 3];
    v ^= hb; hb *= 0x58f38dedu; v *= hb; v ^= v >> 16;
    w[i] = v;
  }
  u128 is_ = ((u128)(((uint64_t)w[0]) | ((uint64_t)w[1] << 32)) << 64)
           | (u128)(((uint64_t)w[2]) | ((uint64_t)w[3] << 32));
  u128 iq  = ((u128)(((uint64_t)w[4]) | ((uint64_t)w[5] << 32)) << 64)
           | (u128)(((uint64_t)w[6]) | ((uint64_t)w[7] << 32));
  inc = (iq << 1) | (u128)1;
  state = inc; state += is_; state = state * PCG_MUL_128 + inc;
}

static inline uint64_t xslrr_h(u128 s) {
  uint64_t x = (uint64_t)(s >> 64) ^ (uint64_t)s;
  unsigned r = (unsigned)(s >> 122);
  return (x >> r) | (x << ((64u - r) & 63u));
}

__device__ __forceinline__ void dev_seed(u128& state, u128& inc) {
  uint32_t hc = 0x43b0d7e5u;
  auto hashmix = [&hc](uint32_t v) -> uint32_t {
    v ^= hc; hc *= 0x931e8875u; v *= hc; v ^= v >> 16; return v;
  };
  uint32_t pool[4];
  for (int i = 0; i < 4; ++i) pool[i] = hashmix(0u);
  for (int s = 0; s < 4; ++s)
    for (int d = 0; d < 4; ++d)
      if (s != d) {
        uint32_t h = hashmix(pool[s]);
        uint32_t r = pool[d] * 0xca01f9ddu - h * 0x4973f715u;   // subtract
        r ^= r >> 16;
        pool[d] = r;
      }
  uint32_t hb = 0x8b51f9ddu;
  uint32_t w[8];
  for (int i = 0; i < 8; ++i) {
    uint32_t v = pool[i & 3];
    v ^= hb; hb *= 0x58f38dedu; v *= hb; v ^= v >> 16;
    w[i] = v;
  }
  u128 is_ = ((u128)(((uint64_t)w[0]) | ((uint64_t)w[1] << 32)) << 64)
           | (u128)(((uint64_t)w[2]) | ((uint64_t)w[3] << 32));
  u128 iq  = ((u128)(((uint64_t)w[4]) | ((uint64_t)w[5] << 32)) << 64)
           | (u128)(((uint64_t)w[6]) | ((uint64_t)w[7] << 32));
  inc = (iq << 1) | (u128)1;
  state = inc; state += is_; state = state * PCG_MUL_128 + inc;
}

__device__ __forceinline__ u128 dev_advance(u128 state, u128 inc, uint64_t delta) {
  u128 am = 1, ap = 0, cm = PCG_MUL_128, cp = inc;
  while (delta) {
    if (delta & 1) { am = am * cm; ap = ap * cm + cp; }
    cp = (cm + (u128)1) * cp;
    cm = cm * cm;
    delta >>= 1;
  }
  return am * state + ap;
}

__device__ __forceinline__ uint64_t draw_at(u128 state, u128 inc, uint64_t n) {
  u128 s = dev_advance(state, inc, n);
  s = s * PCG_MUL_128 + inc;                // step-then-output
  uint64_t x = (uint64_t)(s >> 64) ^ (uint64_t)s;
  unsigned r = (unsigned)(s >> 122);
  return (x >> r) | (x << ((64u - r) & 63u));
}

// ============================================================================
// params_k: one entry per thread; pack[i] = 10-bit params; zero work counter.
// ============================================================================
__global__ __launch_bounds__(256) void params_k(uint32_t* __restrict__ pack,
                                                ThrTab tt) {
  int i = blockIdx.x * 256 + threadIdx.x;
  if (i >= NK) {
    if (i == NK) pack[NK] = 0;             // work counter reset
    return;
  }
  u128 state, inc;
  dev_seed(state, inc);
  uint64_t a = draw_at(state, inc, (uint64_t)(i >> 1));
  uint32_t u = (i & 1) ? (uint32_t)(a >> 32) : (uint32_t)a;
  int si = (int)(((uint64_t)u * 3ull) >> 32);
  uint64_t ud = draw_at(state, inc, (uint64_t)(5000 + i));
  double d = (double)(ud >> 11) * (1.0 / 9007199254740992.0);
  int c0 = 0, c1 = 0, c2 = 0;
  #pragma unroll
  for (int v = 0; v < 84; ++v) {
    c0 += (d >= tt.t[0][v]) ? 1 : 0;
    c1 += (d >= tt.t[1][v]) ? 1 : 0;
    c2 += (d >= tt.t[2][v]) ? 1 : 0;
  }
  int dil = 1 + ((si == 0) ? c0 : ((si == 1) ? c1 : c2));
  uint64_t p6 = draw_at(state, inc, (uint64_t)(15000 + (i >> 1)));
  uint32_t pu = (i & 1) ? (uint32_t)(p6 >> 32) : (uint32_t)p6;
  int pad = (int)(pu >> 31);
  pack[i] = (uint32_t)si | ((uint32_t)dil << 2) | ((uint32_t)pad << 9);
}

// ============================================================================
// Conv + max/ppv, FP16-LDS + __hfma2 + packed epilogue (v_pk_max_f16 /
// v_pk_add_i16 via ext-vector builtins) + dynamic work queue.
// xs[t][16 batches] as __half (32 B/row, row 512 = zeros). Lane (tl=lane>>1,
// bh=lane&1) reads float4 = 4 half2 = 8 batches at one t (conflict-free
// ds_read_b128). acc init = bias.
// ============================================================================
template<int KS>
__device__ __forceinline__ void conv_core(const float4* __restrict__ xs4,
                                          const __half2* wh2, __half2 bvh2,
                                          int twop, int dil, int L,
                                          int tl, int bh,
                                          h2v* mh, s2v* ch) {
  const h2v zero2 = (h2v)0;
  int coreEnd = (L < 512) ? L : 512;
  int nch = (L + 31) >> 5;
  for (int c = 0; c < nch; ++c) {
    int t0 = c << 5;
    int t = t0 + tl;
    __half2 acc[4];
    #pragma unroll
    for (int r = 0; r < 4; ++r) acc[r] = bvh2;
    if (t0 >= twop && t0 + 32 <= coreEnd) {
      // fast path: every tap in-range; pointer walk, no clamps
      const float4* p = xs4 + (unsigned)(t - twop) * 2 + bh;
      #pragma unroll
      for (int j = 0; j < KS; ++j) {
        float4 v4 = *p;
        union { float4 v; __half2 h[4]; } u;
        u.v = v4;
        __half2 wj = wh2[j];
        #pragma unroll
        for (int r = 0; r < 4; ++r) acc[r] = __hfma2(wj, u.h[r], acc[r]);
        p += (unsigned)dil * 2;
      }
    } else {
      // boundary chunk: umin clamp to zero row (negatives wrap -> 512)
      int idx = t - twop;
      #pragma unroll
      for (int j = 0; j < KS; ++j) {
        unsigned ci = (unsigned)idx;
        ci = (ci > 512u) ? 512u : ci;
        float4 v4 = xs4[ci * 2 + bh];
        union { float4 v; __half2 h[4]; } u;
        u.v = v4;
        __half2 wj = wh2[j];
        #pragma unroll
        for (int r = 0; r < 4; ++r) acc[r] = __hfma2(wj, u.h[r], acc[r]);
        idx += dil;
      }
    }
    if (t < L) {
      #pragma unroll
      for (int r = 0; r < 4; ++r) {
        union { __half2 h; h2v v; } cv;
        cv.h = acc[r];
        mh[r] = __builtin_elementwise_max(mh[r], cv.v);
        ch[r] -= (cv.v > zero2);             // mask = -1 per true -> +1
      }
    }
  }
}

__global__ __launch_bounds__(512) void conv_feat_k(const float* __restrict__ x,
                                                   const float* __restrict__ W,
                                                   const float* __restrict__ bias,
                                                   uint32_t* __restrict__ pack,
                                                   float failDiag,
                                                   float* __restrict__ out) {
  __shared__ float4 xs4[513 * 2];    // 16 halves per t; row 512 = zeros (16.4 KB)
  int tid = threadIdx.x;

  // stage batch-transposed fp16, once per block: flat = t*2 + bh
  #pragma unroll
  for (int q = 0; q < 2; ++q) {
    int flat = q * 512 + tid;        // 0..1023
    int t = flat >> 1, bh = flat & 1;
    union { __half h[8]; float4 v; } u;
    #pragma unroll
    for (int r = 0; r < 8; ++r)
      u.h[r] = __float2half(x[(8 * bh + r) * 512 + t]);
    xs4[flat] = u.v;
  }
  if (tid < 2) xs4[512 * 2 + tid] = make_float4(0.f, 0.f, 0.f, 0.f);

  int lane = tid & 63;
  int tl = lane >> 1, bh = lane & 1;
  __syncthreads();                   // the only barrier

  for (;;) {
    int k;
    if (lane == 0) k = (int)atomicAdd(&pack[NK], 1u);
    k = __shfl(k, 0);
    if (k >= NK) break;

    uint32_t bits = pack[k] & 1023u;
    int ks  = 7 + 2 * (int)(bits & 3);
    int dil = (int)((bits >> 2) & 127);
    int pad = (int)(bits >> 9);
    int twop = (ks - 1) * dil * pad;
    int L = 512 + 2 * twop - dil * (ks - 1);
    float w10 = W[k * 11 + 10], w8 = W[k * 11 + 8];
    int ksW = (w10 != 0.0f) ? 11 : ((w8 != 0.0f) ? 9 : 7);
    if (failDiag != 0.0f || ks != ksW) {   // diag (never taken when correct)
      float diag = (failDiag != 0.0f) ? failDiag : 6500000.0f;
      if (lane < 16) {
        out[(size_t)lane * 20000 + 2 * k]     = diag;
        out[(size_t)lane * 20000 + 2 * k + 1] = diag;
      }
      continue;
    }

    __half2 wh2[11];
    #pragma unroll
    for (int j = 0; j < 11; ++j) wh2[j] = __float2half2_rn(W[k * 11 + j]);
    __half2 bvh2 = __float2half2_rn(bias[k]);

    h2v mh[4];
    s2v ch[4];
    #pragma unroll
    for (int r = 0; r < 4; ++r) {
      mh[r] = (h2v)(-__builtin_huge_valf16());
      ch[r] = (s2v)0;
    }
    if (ks == 7)       conv_core<7>(xs4, wh2, bvh2, twop, dil, L, tl, bh, mh, ch);
    else if (ks == 9)  conv_core<9>(xs4, wh2, bvh2, twop, dil, L, tl, bh, mh, ch);
    else               conv_core<11>(xs4, wh2, bvh2, twop, dil, L, tl, bh, mh, ch);

    float m[8];
    int cn[8];
    #pragma unroll
    for (int r = 0; r < 4; ++r) {
      m[2 * r]      = (float)mh[r].x;
      m[2 * r + 1]  = (float)mh[r].y;
      cn[2 * r]     = (int)ch[r].x;
      cn[2 * r + 1] = (int)ch[r].y;
    }
    // reduce over tl (lane bits 1..5); bh (bit 0) preserved
    #pragma unroll
    for (int off = 2; off <= 32; off <<= 1) {
      #pragma unroll
      for (int r = 0; r < 8; ++r) {
        m[r] = fmaxf(m[r], __shfl_xor(m[r], off));
        cn[r] += __shfl_xor(cn[r], off);
      }
    }
    if (tl == 0) {                   // lanes 0,1 hold batches 8*bh + r
      float invL = 1.0f / (float)L;
      #pragma unroll
      for (int r = 0; r < 8; ++r) {
        size_t b = (size_t)(8 * bh + r);
        out[b * 20000 + 2 * k]     = m[r];
        out[b * 20000 + 2 * k + 1] = (float)cn[r] * invL;
      }
    }
  }
}

extern "C" void kernel_launch(void* const* d_in, const int* in_sizes, int n_in,
                              void* d_out, int out_size, void* d_ws, size_t ws_size,
                              hipStream_t stream) {
  (void)out_size;
  const float *x = nullptr, *W = nullptr, *bias = nullptr;
  for (int i = 0; i < n_in; ++i) {
    int sz = in_sizes[i];
    if (sz == 16 * 512)      x    = (const float*)d_in[i];
    else if (sz == NK * 11)  W    = (const float*)d_in[i];
    else if (sz == NK)       bias = (const float*)d_in[i];
  }
  float failDiag = 0.0f;
  if (!x || !W || !bias) {
    failDiag = 9000000.0f;
    x = (const float*)d_in[0]; W = (const float*)d_in[1]; bias = (const float*)d_in[2];
  }

  // host stream for oracle + rejection check (off the timed path)
  static uint64_t hs[20000];
  {
    u128 st, inc; host_seed(st, inc);
    for (int i = 0; i < 20000; ++i) { st = st * PCG_MUL_128 + inc; hs[i] = xslrr_h(st); }
  }
  double d0 = (double)(hs[0] >> 11) * (1.0 / 9007199254740992.0);
  if (failDiag == 0.0f && fabs(d0 - 0.6369616873214543) >= 1.0e-15)
    failDiag = 4000000.0f;
  int rejected = 0;
  for (int i = 0; i < 5000; ++i)
    if ((uint32_t)hs[i] == 0u || (uint32_t)(hs[i] >> 32) == 0u) { rejected = 1; break; }

  // exact dil thresholds: t[si][v-2] = min d with pow(2, hi*d) >= v (glibc)
  static ThrTab tt;
  for (int si = 0; si < 3; ++si) {
    int ksv = 7 + 2 * si;
    double hi = log2((double)(511 / (ksv - 1)));
    double dmax = nextafter(1.0, 0.0);
    for (int v = 2; v <= 85; ++v) {
      if (pow(2.0, hi * dmax) < (double)v) { tt.t[si][v - 2] = 2.0; continue; }
      uint64_t lo = 0, hb;
      memcpy(&hb, &dmax, 8);
      while (hb - lo > 1) {
        uint64_t mid = lo + (hb - lo) / 2;
        double dm;
        memcpy(&dm, &mid, 8);
        if (pow(2.0, hi * dm) >= (double)v) hb = mid; else lo = mid;
      }
      double tv;
      memcpy(&tv, &hb, 8);
      tt.t[si][v - 2] = tv;
    }
  }

  uint32_t* dpack = (uint32_t*)d_ws;

  if (!rejected && ws_size >= WS_NEEDED) {
    params_k<<<(NK + 256) / 256, 256, 0, stream>>>(dpack, tt);   // covers i <= NK
    conv_feat_k<<<NBLK, 512, 0, stream>>>(x, W, bias, dpack, failDiag,
                                          (float*)d_out);
  } else {
    // fallback (never for this seed): host pack, one 40 KB H2D incl. counter=0
    static uint32_t h_pack[NK + 1];
    {
      int pos32 = 0;
      auto nx32 = [&](int& p) -> uint32_t {
        uint64_t v = hs[p >> 1];
        uint32_t u = (p & 1) ? (uint32_t)(v >> 32) : (uint32_t)v;
        ++p; return u;
      };
      static int ksA[NK];
      for (int i = 0; i < NK; ++i) {
        uint64_t m; uint32_t u;
        do { u = nx32(pos32); m = (uint64_t)u * 3ull; } while ((uint32_t)m == 0u);
        ksA[i] = (int)(m >> 32);
      }
      int u64pos = (pos32 + 1) >> 1;
      static int dilA[NK];
      for (int i = 0; i < NK; ++i) {
        double d = (double)(hs[u64pos + i] >> 11) * (1.0 / 9007199254740992.0);
        int ksv = 7 + 2 * ksA[i];
        double hi2 = log2((double)(511 / (ksv - 1)));
        dilA[i] = (int)floor(pow(2.0, hi2 * d));
      }
      int p32 = 2 * (u64pos + NK);
      for (int i = 0; i < NK; ++i) {
        int pad = (int)(nx32(p32) >> 31);
        h_pack[i] = (uint32_t)ksA[i] | ((uint32_t)dilA[i] << 2)
                  | ((uint32_t)pad << 9);
      }
      h_pack[NK] = 0;   // work counter
    }
    (void)hipMemcpyAsync(dpack, h_pack, sizeof(h_pack), hipMemcpyHostToDevice,
                         stream);
    conv_feat_k<<<NBLK, 512, 0, stream>>>(x, W, bias, dpack, failDiag,
                                          (float*)d_out);
  }
}

// Round 26
// 71.793 us; speedup vs baseline: 3.2461x; 3.2461x over previous
//
#include <hip/hip_runtime.h>
#include <hip/hip_fp16.h>
#include <math.h>
#include <stdint.h>
#include <string.h>

typedef unsigned __int128 u128;
typedef _Float16 h2v __attribute__((ext_vector_type(2)));
typedef short    s2v __attribute__((ext_vector_type(2)));

#define NK 10000
#define KPB 8              // one k per wave; grid = NK/KPB = 1250

#define PCG_MUL_128 ((((u128)0x2360ed051fc65da4ULL) << 64) | 0x4385df649fccf645ULL)

// d_ws layout: pack (unsorted) then sorted
#define SORT_OFF   (NK * 4)                // 40000
#define WS_NEEDED  (SORT_OFF + NK * 4)     // 80000

struct ThrTab { double t[3][84]; };        // dil thresholds, v = 2..85

// ============================================================================
// numpy default_rng(0) chain (verified r8-r25): SeedSequence mix = x*L - y*R
// (SUBTRACT); PCG64 XSL-RR step-then-output; integers -> buffered Lemire32,
// low half first. Device regenerates draws per-thread via advance() skip-ahead.
// ============================================================================
static void host_seed(u128& state, u128& inc) {
  uint32_t hc = 0x43b0d7e5u;
  auto hashmix = [&hc](uint32_t v) -> uint32_t {
    v ^= hc; hc *= 0x931e8875u; v *= hc; v ^= v >> 16; return v;
  };
  uint32_t pool[4];
  for (int i = 0; i < 4; ++i) pool[i] = hashmix(0u);
  for (int s = 0; s < 4; ++s)
    for (int d = 0; d < 4; ++d)
      if (s != d) {
        uint32_t h = hashmix(pool[s]);
        uint32_t r = pool[d] * 0xca01f9ddu - h * 0x4973f715u;   // subtract
        r ^= r >> 16;
        pool[d] = r;
      }
  uint32_t hb = 0x8b51f9ddu;
  uint32_t w[8];
  for (int i = 0; i < 8; ++i) {
    uint32_t v = pool[i & 3];
    v ^= hb; hb *= 0x58f38dedu; v *= hb; v ^= v >> 16;
    w[i] = v;
  }
  u128 is_ = ((u128)(((uint64_t)w[0]) | ((uint64_t)w[1] << 32)) << 64)
           | (u128)(((uint64_t)w[2]) | ((uint64_t)w[3] << 32));
  u128 iq  = ((u128)(((uint64_t)w[4]) | ((uint64_t)w[5] << 32)) << 64)
           | (u128)(((uint64_t)w[6]) | ((uint64_t)w[7] << 32));
  inc = (iq << 1) | (u128)1;
  state = inc; state += is_; state = state * PCG_MUL_128 + inc;
}

static inline uint64_t xslrr_h(u128 s) {
  uint64_t x = (uint64_t)(s >> 64) ^ (uint64_t)s;
  unsigned r = (unsigned)(s >> 122);
  return (x >> r) | (x << ((64u - r) & 63u));
}

__device__ __forceinline__ void dev_seed(u128& state, u128& inc) {
  uint32_t hc = 0x43b0d7e5u;
  auto hashmix = [&hc](uint32_t v) -> uint32_t {
    v ^= hc; hc *= 0x931e8875u; v *= hc; v ^= v >> 16; return v;
  };
  uint32_t pool[4];
  for (int i = 0; i < 4; ++i) pool[i] = hashmix(0u);
  for (int s = 0; s < 4; ++s)
    for (int d = 0; d < 4; ++d)
      if (s != d) {
        uint32_t h = hashmix(pool[s]);
        uint32_t r = pool[d] * 0xca01f9ddu - h * 0x4973f715u;   // subtract
        r ^= r >> 16;
        pool[d] = r;
      }
  uint32_t hb = 0x8b51f9ddu;
  uint32_t w[8];
  for (int i = 0; i < 8; ++i) {
    uint32_t v = pool[i & 3];
    v ^= hb; hb *= 0x58f38dedu; v *= hb; v ^= v >> 16;
    w[i] = v;
  }
  u128 is_ = ((u128)(((uint64_t)w[0]) | ((uint64_t)w[1] << 32)) << 64)
           | (u128)(((uint64_t)w[2]) | ((uint64_t)w[3] << 32));
  u128 iq  = ((u128)(((uint64_t)w[4]) | ((uint64_t)w[5] << 32)) << 64)
           | (u128)(((uint64_t)w[6]) | ((uint64_t)w[7] << 32));
  inc = (iq << 1) | (u128)1;
  state = inc; state += is_; state = state * PCG_MUL_128 + inc;
}

__device__ __forceinline__ u128 dev_advance(u128 state, u128 inc, uint64_t delta) {
  u128 am = 1, ap = 0, cm = PCG_MUL_128, cp = inc;
  while (delta) {
    if (delta & 1) { am = am * cm; ap = ap * cm + cp; }
    cp = (cm + (u128)1) * cp;
    cm = cm * cm;
    delta >>= 1;
  }
  return am * state + ap;
}

__device__ __forceinline__ uint64_t draw_at(u128 state, u128 inc, uint64_t n) {
  u128 s = dev_advance(state, inc, n);
  s = s * PCG_MUL_128 + inc;                // step-then-output
  uint64_t x = (uint64_t)(s >> 64) ^ (uint64_t)s;
  unsigned r = (unsigned)(s >> 122);
  return (x >> r) | (x << ((64u - r) & 63u));
}

// ============================================================================
// params_k (r18 verbatim): 40 blocks x 256, one entry per thread.
// ============================================================================
__global__ __launch_bounds__(256) void params_k(uint32_t* __restrict__ pack,
                                                ThrTab tt) {
  int i = blockIdx.x * 256 + threadIdx.x;
  if (i >= NK) return;
  u128 state, inc;
  dev_seed(state, inc);
  uint64_t a = draw_at(state, inc, (uint64_t)(i >> 1));
  uint32_t u = (i & 1) ? (uint32_t)(a >> 32) : (uint32_t)a;
  int si = (int)(((uint64_t)u * 3ull) >> 32);
  uint64_t ud = draw_at(state, inc, (uint64_t)(5000 + i));
  double d = (double)(ud >> 11) * (1.0 / 9007199254740992.0);
  int c0 = 0, c1 = 0, c2 = 0;
  #pragma unroll
  for (int v = 0; v < 84; ++v) {
    c0 += (d >= tt.t[0][v]) ? 1 : 0;
    c1 += (d >= tt.t[1][v]) ? 1 : 0;
    c2 += (d >= tt.t[2][v]) ? 1 : 0;
  }
  int dil = 1 + ((si == 0) ? c0 : ((si == 1) ? c1 : c2));
  uint64_t p6 = draw_at(state, inc, (uint64_t)(15000 + (i >> 1)));
  uint32_t pu = (i & 1) ? (uint32_t)(p6 >> 32) : (uint32_t)p6;
  int pad = (int)(pu >> 31);
  pack[i] = ((uint32_t)i << 10) | (uint32_t)si | ((uint32_t)dil << 2)
          | ((uint32_t)pad << 9);
}

// ============================================================================
// sort_k (r16/r18 verbatim): counting sort by L descending (bucket = 1022-L)
// ============================================================================
__global__ __launch_bounds__(1024) void sort_k(const uint32_t* __restrict__ pack,
                                               uint32_t* __restrict__ sorted) {
  __shared__ int hist[1024];
  __shared__ int offs[1024];
  int tid = threadIdx.x;
  hist[tid] = 0;
  __syncthreads();
  for (int p = 0; p < 10; ++p) {
    int i = tid + p * 1024;
    if (i < NK) {
      uint32_t bits = pack[i] & 1023u;
      int ks = 7 + 2 * (int)(bits & 3), dil = (int)((bits >> 2) & 127);
      int pad = (int)(bits >> 9);
      int twop = (ks - 1) * dil * pad;
      int L = 512 + 2 * twop - dil * (ks - 1);
      atomicAdd(&hist[1022 - L], 1);
    }
  }
  __syncthreads();
  int own = hist[tid];
  for (int off = 1; off < 1024; off <<= 1) {
    int v = (tid >= off) ? hist[tid - off] : 0;
    __syncthreads();
    hist[tid] += v;
    __syncthreads();
  }
  offs[tid] = hist[tid] - own;
  __syncthreads();
  for (int p = 0; p < 10; ++p) {
    int i = tid + p * 1024;
    if (i < NK) {
      uint32_t e = pack[i];
      uint32_t bits = e & 1023u;
      int ks = 7 + 2 * (int)(bits & 3), dil = (int)((bits >> 2) & 127);
      int pad = (int)(bits >> 9);
      int twop = (ks - 1) * dil * pad;
      int L = 512 + 2 * twop - dil * (ks - 1);
      int idx = atomicAdd(&offs[1022 - L], 1);
      sorted[idx] = e;
    }
  }
}

// ============================================================================
// Conv + max/ppv (r25-verified body, r23-proven static sorted assignment):
// FP16-LDS xs[t][16 batches] (32 B/row, row 512 = zeros); lane (tl=lane>>1,
// bh=lane&1) reads float4 = 4 half2 = 8 batches at one t (conflict-free
// ds_read_b128). MAC chain = __hfma2 (bias in acc init); chunk epilogue =
// packed v_pk_max_f16 + mask-subtract (v_pk_add_i16) via ext-vector builtins.
// ============================================================================
template<int KS>
__device__ __forceinline__ void conv_core(const float4* __restrict__ xs4,
                                          const __half2* wh2, __half2 bvh2,
                                          int twop, int dil, int L,
                                          int tl, int bh,
                                          h2v* mh, s2v* ch) {
  const h2v zero2 = (h2v)0;
  int coreEnd = (L < 512) ? L : 512;
  int nch = (L + 31) >> 5;
  for (int c = 0; c < nch; ++c) {
    int t0 = c << 5;
    int t = t0 + tl;
    __half2 acc[4];
    #pragma unroll
    for (int r = 0; r < 4; ++r) acc[r] = bvh2;
    if (t0 >= twop && t0 + 32 <= coreEnd) {
      // fast path: every tap in-range; pointer walk, no clamps
      const float4* p = xs4 + (unsigned)(t - twop) * 2 + bh;
      #pragma unroll
      for (int j = 0; j < KS; ++j) {
        float4 v4 = *p;
        union { float4 v; __half2 h[4]; } u;
        u.v = v4;
        __half2 wj = wh2[j];
        #pragma unroll
        for (int r = 0; r < 4; ++r) acc[r] = __hfma2(wj, u.h[r], acc[r]);
        p += (unsigned)dil * 2;
      }
    } else {
      // boundary chunk: umin clamp to zero row (negatives wrap -> 512)
      int idx = t - twop;
      #pragma unroll
      for (int j = 0; j < KS; ++j) {
        unsigned ci = (unsigned)idx;
        ci = (ci > 512u) ? 512u : ci;
        float4 v4 = xs4[ci * 2 + bh];
        union { float4 v; __half2 h[4]; } u;
        u.v = v4;
        __half2 wj = wh2[j];
        #pragma unroll
        for (int r = 0; r < 4; ++r) acc[r] = __hfma2(wj, u.h[r], acc[r]);
        idx += dil;
      }
    }
    if (t < L) {
      #pragma unroll
      for (int r = 0; r < 4; ++r) {
        union { __half2 h; h2v v; } cv;
        cv.h = acc[r];
        mh[r] = __builtin_elementwise_max(mh[r], cv.v);
        ch[r] -= (cv.v > zero2);             // mask = -1 per true -> +1
      }
    }
  }
}

__global__ __launch_bounds__(512) void conv_feat_k(const float* __restrict__ x,
                                                   const float* __restrict__ W,
                                                   const float* __restrict__ bias,
                                                   const uint32_t* __restrict__ entries,
                                                   float failDiag,
                                                   float* __restrict__ out) {
  __shared__ float4 xs4[513 * 2];    // 16 halves per t; row 512 = zeros (16.4 KB)
  int tid = threadIdx.x;

  // stage batch-transposed fp16, once per block: flat = t*2 + bh
  #pragma unroll
  for (int q = 0; q < 2; ++q) {
    int flat = q * 512 + tid;        // 0..1023
    int t = flat >> 1, bh = flat & 1;
    union { __half h[8]; float4 v; } u;
    #pragma unroll
    for (int r = 0; r < 8; ++r)
      u.h[r] = __float2half(x[(8 * bh + r) * 512 + t]);
    xs4[flat] = u.v;
  }
  if (tid < 2) xs4[512 * 2 + tid] = make_float4(0.f, 0.f, 0.f, 0.f);

  int wave = tid >> 6, lane = tid & 63;
  int tl = lane >> 1, bh = lane & 1;
  uint32_t e = entries[blockIdx.x * KPB + wave];
  int k = (int)(e >> 10);
  uint32_t bits = e & 1023u;
  __syncthreads();                   // the only barrier

  int ks  = 7 + 2 * (int)(bits & 3);
  int dil = (int)((bits >> 2) & 127);
  int pad = (int)(bits >> 9);
  int twop = (ks - 1) * dil * pad;
  int L = 512 + 2 * twop - dil * (ks - 1);
  float w10 = W[k * 11 + 10], w8 = W[k * 11 + 8];
  int ksW = (w10 != 0.0f) ? 11 : ((w8 != 0.0f) ? 9 : 7);
  if (failDiag != 0.0f || ks != ksW) {   // diag (never taken when correct)
    float diag = (failDiag != 0.0f) ? failDiag : 6500000.0f;
    if (lane < 16) {
      out[(size_t)lane * 20000 + 2 * k]     = diag;
      out[(size_t)lane * 20000 + 2 * k + 1] = diag;
    }
    return;
  }

  __half2 wh2[11];
  #pragma unroll
  for (int j = 0; j < 11; ++j) wh2[j] = __float2half2_rn(W[k * 11 + j]);
  __half2 bvh2 = __float2half2_rn(bias[k]);

  h2v mh[4];
  s2v ch[4];
  #pragma unroll
  for (int r = 0; r < 4; ++r) {
    mh[r] = (h2v)(-__builtin_huge_valf16());
    ch[r] = (s2v)0;
  }
  if (ks == 7)       conv_core<7>(xs4, wh2, bvh2, twop, dil, L, tl, bh, mh, ch);
  else if (ks == 9)  conv_core<9>(xs4, wh2, bvh2, twop, dil, L, tl, bh, mh, ch);
  else               conv_core<11>(xs4, wh2, bvh2, twop, dil, L, tl, bh, mh, ch);

  float m[8];
  int cn[8];
  #pragma unroll
  for (int r = 0; r < 4; ++r) {
    m[2 * r]      = (float)mh[r].x;
    m[2 * r + 1]  = (float)mh[r].y;
    cn[2 * r]     = (int)ch[r].x;
    cn[2 * r + 1] = (int)ch[r].y;
  }
  // reduce over tl (lane bits 1..5); bh (bit 0) preserved
  #pragma unroll
  for (int off = 2; off <= 32; off <<= 1) {
    #pragma unroll
    for (int r = 0; r < 8; ++r) {
      m[r] = fmaxf(m[r], __shfl_xor(m[r], off));
      cn[r] += __shfl_xor(cn[r], off);
    }
  }
  if (tl == 0) {                     // lanes 0,1 hold batches 8*bh + r
    float invL = 1.0f / (float)L;
    #pragma unroll
    for (int r = 0; r < 8; ++r) {
      size_t b = (size_t)(8 * bh + r);
      out[b * 20000 + 2 * k]     = m[r];
      out[b * 20000 + 2 * k + 1] = (float)cn[r] * invL;
    }
  }
}

extern "C" void kernel_launch(void* const* d_in, const int* in_sizes, int n_in,
                              void* d_out, int out_size, void* d_ws, size_t ws_size,
                              hipStream_t stream) {
  (void)out_size;
  const float *x = nullptr, *W = nullptr, *bias = nullptr;
  for (int i = 0; i < n_in; ++i) {
    int sz = in_sizes[i];
    if (sz == 16 * 512)      x    = (const float*)d_in[i];
    else if (sz == NK * 11)  W    = (const float*)d_in[i];
    else if (sz == NK)       bias = (const float*)d_in[i];
  }
  float failDiag = 0.0f;
  if (!x || !W || !bias) {
    failDiag = 9000000.0f;
    x = (const float*)d_in[0]; W = (const float*)d_in[1]; bias = (const float*)d_in[2];
  }

  // host stream for oracle + rejection check (off the timed path)
  static uint64_t hs[20000];
  {
    u128 st, inc; host_seed(st, inc);
    for (int i = 0; i < 20000; ++i) { st = st * PCG_MUL_128 + inc; hs[i] = xslrr_h(st); }
  }
  double d0 = (double)(hs[0] >> 11) * (1.0 / 9007199254740992.0);
  if (failDiag == 0.0f && fabs(d0 - 0.6369616873214543) >= 1.0e-15)
    failDiag = 4000000.0f;
  int rejected = 0;
  for (int i = 0; i < 5000; ++i)
    if ((uint32_t)hs[i] == 0u || (uint32_t)(hs[i] >> 32) == 0u) { rejected = 1; break; }

  // exact dil thresholds: t[si][v-2] = min d with pow(2, hi*d) >= v (glibc)
  static ThrTab tt;
  for (int si = 0; si < 3; ++si) {
    int ksv = 7 + 2 * si;
    double hi = log2((double)(511 / (ksv - 1)));
    double dmax = nextafter(1.0, 0.0);
    for (int v = 2; v <= 85; ++v) {
      if (pow(2.0, hi * dmax) < (double)v) { tt.t[si][v - 2] = 2.0; continue; }
      uint64_t lo = 0, hb;
      memcpy(&hb, &dmax, 8);
      while (hb - lo > 1) {
        uint64_t mid = lo + (hb - lo) / 2;
        double dm;
        memcpy(&dm, &mid, 8);
        if (pow(2.0, hi * dm) >= (double)v) hb = mid; else lo = mid;
      }
      double tv;
      memcpy(&tv, &hb, 8);
      tt.t[si][v - 2] = tv;
    }
  }

  uint32_t* dpack = (uint32_t*)d_ws;
  uint32_t* dsort = (uint32_t*)((char*)d_ws + SORT_OFF);

  if (!rejected && ws_size >= WS_NEEDED) {
    params_k<<<(NK + 255) / 256, 256, 0, stream>>>(dpack, tt);
    sort_k<<<1, 1024, 0, stream>>>(dpack, dsort);
    conv_feat_k<<<NK / KPB, 512, 0, stream>>>(x, W, bias, dsort, failDiag,
                                              (float*)d_out);
  } else {
    // fallback (never for this seed): host pack + sort, one 40 KB H2D
    static uint32_t h_entries[NK];
    {
      int pos32 = 0;
      auto nx32 = [&](int& p) -> uint32_t {
        uint64_t v = hs[p >> 1];
        uint32_t u = (p & 1) ? (uint32_t)(v >> 32) : (uint32_t)v;
        ++p; return u;
      };
      static int ksA[NK], dilA[NK], padA[NK];
      for (int i = 0; i < NK; ++i) {
        uint64_t m; uint32_t u;
        do { u = nx32(pos32); m = (uint64_t)u * 3ull; } while ((uint32_t)m == 0u);
        ksA[i] = (int)(m >> 32);
      }
      int u64pos = (pos32 + 1) >> 1;
      for (int i = 0; i < NK; ++i) {
        double d = (double)(hs[u64pos + i] >> 11) * (1.0 / 9007199254740992.0);
        int ksv = 7 + 2 * ksA[i];
        double hi2 = log2((double)(511 / (ksv - 1)));
        dilA[i] = (int)floor(pow(2.0, hi2 * d));
      }
      int p32 = 2 * (u64pos + NK);
      for (int i = 0; i < NK; ++i) padA[i] = (int)(nx32(p32) >> 31);
      static int cnt2[1024], off2[1024];
      for (int b = 0; b < 1024; ++b) cnt2[b] = 0;
      for (int i = 0; i < NK; ++i) {
        int ksv = 7 + 2 * ksA[i];
        int twop = (ksv - 1) * dilA[i] * padA[i];
        int L = 512 + 2 * twop - dilA[i] * (ksv - 1);
        cnt2[1022 - L]++;
      }
      int acc = 0;
      for (int b = 0; b < 1024; ++b) { off2[b] = acc; acc += cnt2[b]; }
      for (int i = 0; i < NK; ++i) {
        int ksv = 7 + 2 * ksA[i];
        int twop = (ksv - 1) * dilA[i] * padA[i];
        int L = 512 + 2 * twop - dilA[i] * (ksv - 1);
        uint32_t bits = (uint32_t)ksA[i] | ((uint32_t)dilA[i] << 2)
                      | ((uint32_t)padA[i] << 9);
        h_entries[off2[1022 - L]++] = ((uint32_t)i << 10) | bits;
      }
    }
    (void)hipMemcpyAsync(dsort, h_entries, sizeof(h_entries),
                         hipMemcpyHostToDevice, stream);
    conv_feat_k<<<NK / KPB, 512, 0, stream>>>(x, W, bias, dsort, failDiag,
                                              (float*)d_out);
  }
}